// Round 1
// baseline (230.656 us; speedup 1.0000x reference)
//
#include <hip/hip_runtime.h>

typedef __attribute__((ext_vector_type(8))) short short8;
typedef __attribute__((ext_vector_type(4))) float f32x4;

#define N_ATOMS 4096
#define N_NEIGH 32
#define IN_F 128
#define HID 256
#define OUT_F 128
#define N_SPECIES 64
#define GRP 4
#define MAX_GROUPS 1088  // sum ceil(c_s/4) <= 4096/4 + 63

__device__ __forceinline__ unsigned short f2bf(float f) {
  unsigned u = __float_as_uint(f);
  u += 0x7FFF + ((u >> 16) & 1);   // round-to-nearest-even
  return (unsigned short)(u >> 16);
}
__device__ __forceinline__ float bf2f(unsigned short h) {
  return __uint_as_float(((unsigned)h) << 16);
}

// ---------- kernel 1: split W1/W2 fp32 -> bf16 hi/lo planes in ws ----------
__global__ __launch_bounds__(256) void wsplit_kernel(
    const float* __restrict__ W1, const float* __restrict__ W2,
    unsigned short* __restrict__ w1h, unsigned short* __restrict__ w1l,
    unsigned short* __restrict__ w2h, unsigned short* __restrict__ w2l) {
  const int NV = (N_SPECIES * HID * IN_F) / 4;  // float4 count per matrix (same for W2)
  for (int v = blockIdx.x * blockDim.x + threadIdx.x; v < 2 * NV;
       v += gridDim.x * blockDim.x) {
    const float4* src; unsigned short* dh; unsigned short* dl; int j;
    if (v < NV) { src = (const float4*)W1; dh = w1h; dl = w1l; j = v; }
    else        { src = (const float4*)W2; dh = w2h; dl = w2l; j = v - NV; }
    float4 f = src[j];
    float vv[4] = {f.x, f.y, f.z, f.w};
    ushort4 h, l;
    unsigned short hb;
    hb = f2bf(vv[0]); h.x = hb; l.x = f2bf(vv[0] - bf2f(hb));
    hb = f2bf(vv[1]); h.y = hb; l.y = f2bf(vv[1] - bf2f(hb));
    hb = f2bf(vv[2]); h.z = hb; l.z = f2bf(vv[2] - bf2f(hb));
    hb = f2bf(vv[3]); h.w = hb; l.w = f2bf(vv[3] - bf2f(hb));
    ((ushort4*)dh)[j] = h;
    ((ushort4*)dl)[j] = l;
  }
}

// ---------- kernel 2: counting sort by species + group table ----------
__global__ __launch_bounds__(256) void sort_kernel(
    const int* __restrict__ sp_idx,
    int* __restrict__ atom_order, int* __restrict__ grp_sp,
    int* __restrict__ grp_base, int* __restrict__ grp_cnt,
    int* __restrict__ n_groups) {
  __shared__ int cnt[N_SPECIES], off[N_SPECIES], cur[N_SPECIES], gb[N_SPECIES];
  const int t = threadIdx.x;
  if (t < N_SPECIES) cnt[t] = 0;
  __syncthreads();
  for (int a = t; a < N_ATOMS; a += 256) atomicAdd(&cnt[sp_idx[a]], 1);
  __syncthreads();
  if (t == 0) {
    int o = 0, g = 0;
    for (int s = 0; s < N_SPECIES; ++s) {
      off[s] = o; cur[s] = o; gb[s] = g;
      o += cnt[s];
      g += (cnt[s] + GRP - 1) / GRP;
    }
    *n_groups = g;
  }
  __syncthreads();
  for (int a = t; a < N_ATOMS; a += 256) {
    int s = sp_idx[a];
    atom_order[atomicAdd(&cur[s], 1)] = a;
  }
  if (t < N_SPECIES) {
    const int c = cnt[t], base = off[t], g0 = gb[t];
    const int ng = (c + GRP - 1) / GRP;
    for (int j = 0; j < ng; ++j) {
      grp_sp[g0 + j]   = t;
      grp_base[g0 + j] = base + j * GRP;
      grp_cnt[g0 + j]  = min(GRP, c - j * GRP);
    }
  }
}

// ---------- kernel 3: fused 2-layer MLP, 1 block = 4 waves = 4 atoms (one species) ----------
// LDS per block: W1 chunk hi/lo 2x8KB + W2 chunk hi/lo 2x8KB + per-wave x tile 4x4KB = 48 KB
__global__ __launch_bounds__(256, 2) void mlp_kernel(
    const float* __restrict__ feat,
    const float* __restrict__ b1g, const float* __restrict__ b2g,
    const unsigned short* __restrict__ w1h, const unsigned short* __restrict__ w1l,
    const unsigned short* __restrict__ w2h, const unsigned short* __restrict__ w2l,
    const int* __restrict__ atom_order, const int* __restrict__ grp_sp,
    const int* __restrict__ grp_base, const int* __restrict__ grp_cnt,
    const int* __restrict__ n_groups,
    float* __restrict__ out) {
  const int g = blockIdx.x;
  if (g >= *n_groups) return;
  const int s = grp_sp[g];
  const int abase = grp_base[g];
  const int cnt = grp_cnt[g];
  const int tid = threadIdx.x;
  const int wave = tid >> 6, lane = tid & 63;
  const int q = lane >> 4, r = lane & 15;

  __shared__ unsigned short lw1[2][32 * IN_F];   // [hi/lo][h_local(32) x i(128)], XOR-swizzled
  __shared__ unsigned short lw2[2][OUT_F * 32];  // [hi/lo][o(128) x h_local(32)], XOR-swizzled
  __shared__ float lx[4][N_NEIGH * 32];          // per-wave [n(32) x h_local(32)] fp32, swizzled

  const bool active = (wave < cnt);
  int atom = 0;

  // Feature A-fragments (held in registers all kernel): rows 16*nt + r, k = 32*ks + 8*q + j
  short8 fh[2][4], fl[2][4];
  if (active) {
    atom = atom_order[abase + wave];
    const float* fb = feat + (long)atom * (N_NEIGH * IN_F);
#pragma unroll
    for (int nt = 0; nt < 2; ++nt)
#pragma unroll
      for (int ks = 0; ks < 4; ++ks) {
        const float* p = fb + (16 * nt + r) * IN_F + 32 * ks + 8 * q;
        float4 v0 = *(const float4*)p;
        float4 v1 = *(const float4*)(p + 4);
        float vv[8] = {v0.x, v0.y, v0.z, v0.w, v1.x, v1.y, v1.z, v1.w};
        short8 h8, l8;
#pragma unroll
        for (int j = 0; j < 8; ++j) {
          unsigned short hb = f2bf(vv[j]);
          h8[j] = (short)hb;
          l8[j] = (short)f2bf(vv[j] - bf2f(hb));
        }
        fh[nt][ks] = h8;
        fl[nt][ks] = l8;
      }
  }

  float b2v[8];
#pragma unroll
  for (int ot = 0; ot < 8; ++ot) b2v[ot] = b2g[s * OUT_F + 16 * ot + r];

  f32x4 oacc[2][8] = {};

  const long w1sb = (long)s * (HID * IN_F) * 2;   // species byte offset
  const long w2sb = (long)s * (OUT_F * HID) * 2;

  for (int hc = 0; hc < 8; ++hc) {  // hidden chunk of 32
    __syncthreads();  // previous chunk's LDS reads complete before overwrite
    {
      // wave w stages plane w: 0=w1h 1=w1l 2=w2h 3=w2l; 8 KB each, 8 x 16B per lane.
      const char* gsrc;
      char* lbase;
      if (wave == 0)      { gsrc = (const char*)w1h + w1sb; lbase = (char*)lw1[0]; }
      else if (wave == 1) { gsrc = (const char*)w1l + w1sb; lbase = (char*)lw1[1]; }
      else if (wave == 2) { gsrc = (const char*)w2h + w2sb; lbase = (char*)lw2[0]; }
      else                { gsrc = (const char*)w2l + w2sb; lbase = (char*)lw2[1]; }
      const bool isw1 = (wave < 2);
#pragma unroll
      for (int it = 0; it < 8; ++it) {
        const int b = it * 1024 + lane * 16;  // linear LDS dest byte
        long srcoff;
        if (isw1) {
          // LDS rows = h_local (256 B). Inverse-swizzled source (rule 21 involution).
          const int hl = b >> 8;
          const int within = (b & 255) ^ ((hl & 7) << 4);
          srcoff = (long)(hc * 32 + hl) * (IN_F * 2) + within;
        } else {
          // LDS rows = o (64 B); global row stride HID*2, h-slice at hc*32.
          const int ol = b >> 6;
          const int within = (b & 63) ^ ((ol & 3) << 4);
          srcoff = (long)ol * (HID * 2) + hc * 64 + within;
        }
        __builtin_amdgcn_global_load_lds(
            (const __attribute__((address_space(1))) unsigned int*)(gsrc + srcoff),
            (__attribute__((address_space(3))) unsigned int*)(lbase + b),
            16, 0, 0);
      }
    }
    asm volatile("s_waitcnt vmcnt(0)" ::: "memory");
    __syncthreads();

    if (active) {
      // ---- layer 1: x[32 x 32chunk] = feat(32x128) @ W1chunk^T, 3-term hi/lo split
      f32x4 xacc[2][2] = {};
#pragma unroll
      for (int ks = 0; ks < 4; ++ks) {
#pragma unroll
        for (int ht = 0; ht < 2; ++ht) {
          const int hl = r + 16 * ht;
          int byte = (hl << 8) + ((32 * ks + 8 * q) << 1);
          byte ^= (hl & 7) << 4;
          short8 bh = *(const short8*)((const char*)lw1[0] + byte);
          short8 bl = *(const short8*)((const char*)lw1[1] + byte);
#pragma unroll
          for (int nt = 0; nt < 2; ++nt) {
            xacc[nt][ht] = __builtin_amdgcn_mfma_f32_16x16x32_bf16(fh[nt][ks], bh, xacc[nt][ht], 0, 0, 0);
            xacc[nt][ht] = __builtin_amdgcn_mfma_f32_16x16x32_bf16(fh[nt][ks], bl, xacc[nt][ht], 0, 0, 0);
            xacc[nt][ht] = __builtin_amdgcn_mfma_f32_16x16x32_bf16(fl[nt][ks], bh, xacc[nt][ht], 0, 0, 0);
          }
        }
      }
      // ---- bias + SiLU, write per-wave x tile (fp32, swizzled)
      char* lxw = (char*)lx[wave];
#pragma unroll
      for (int ht = 0; ht < 2; ++ht) {
        const float b1v = b1g[s * HID + hc * 32 + 16 * ht + r];
#pragma unroll
        for (int nt = 0; nt < 2; ++nt)
#pragma unroll
          for (int i = 0; i < 4; ++i) {
            const int n = 16 * nt + 4 * q + i;
            float v = xacc[nt][ht][i] + b1v;
            v = v / (1.0f + __expf(-v));
            int byte = (n << 7) + ((r + 16 * ht) << 2);
            byte ^= (n & 7) << 4;
            *(float*)(lxw + byte) = v;
          }
      }
      // ---- read back as layer-2 A-frags (row n = 16*nt + r, k = 8*q + j), split hi/lo
      short8 ah[2], al[2];
#pragma unroll
      for (int nt = 0; nt < 2; ++nt) {
        const int n = 16 * nt + r;
        const int base_b = (n << 7) + (q << 5);
        const int swz = (n & 7) << 4;
        float4 v0 = *(const float4*)(lxw + (base_b ^ swz));
        float4 v1 = *(const float4*)(lxw + ((base_b + 16) ^ swz));
        float vv[8] = {v0.x, v0.y, v0.z, v0.w, v1.x, v1.y, v1.z, v1.w};
        short8 h8, l8;
#pragma unroll
        for (int j = 0; j < 8; ++j) {
          unsigned short hb = f2bf(vv[j]);
          h8[j] = (short)hb;
          l8[j] = (short)f2bf(vv[j] - bf2f(hb));
        }
        ah[nt] = h8;
        al[nt] = l8;
      }
      // ---- layer 2 partial: out += silu_x_chunk @ W2chunk^T
#pragma unroll
      for (int ot = 0; ot < 8; ++ot) {
        const int ol = r + 16 * ot;
        int byte = (ol << 6) + (q << 4);
        byte ^= (ol & 3) << 4;
        short8 bh = *(const short8*)((const char*)lw2[0] + byte);
        short8 bl = *(const short8*)((const char*)lw2[1] + byte);
#pragma unroll
        for (int nt = 0; nt < 2; ++nt) {
          oacc[nt][ot] = __builtin_amdgcn_mfma_f32_16x16x32_bf16(ah[nt], bh, oacc[nt][ot], 0, 0, 0);
          oacc[nt][ot] = __builtin_amdgcn_mfma_f32_16x16x32_bf16(ah[nt], bl, oacc[nt][ot], 0, 0, 0);
          oacc[nt][ot] = __builtin_amdgcn_mfma_f32_16x16x32_bf16(al[nt], bh, oacc[nt][ot], 0, 0, 0);
        }
      }
    }
  }

  if (active) {
    float* ob = out + (long)atom * (N_NEIGH * OUT_F);
#pragma unroll
    for (int nt = 0; nt < 2; ++nt)
#pragma unroll
      for (int ot = 0; ot < 8; ++ot)
#pragma unroll
        for (int i = 0; i < 4; ++i) {
          ob[(16 * nt + 4 * q + i) * OUT_F + 16 * ot + r] = oacc[nt][ot][i] + b2v[ot];
        }
  }
}

extern "C" void kernel_launch(void* const* d_in, const int* in_sizes, int n_in,
                              void* d_out, int out_size, void* d_ws, size_t ws_size,
                              hipStream_t stream) {
  const float* feat = (const float*)d_in[0];
  const int* sp     = (const int*)d_in[1];
  const float* W1   = (const float*)d_in[2];
  const float* b1   = (const float*)d_in[3];
  const float* W2   = (const float*)d_in[4];
  const float* b2   = (const float*)d_in[5];
  float* out = (float*)d_out;

  char* ws = (char*)d_ws;
  unsigned short* w1h = (unsigned short*)(ws + 0);
  unsigned short* w1l = (unsigned short*)(ws + 4194304);
  unsigned short* w2h = (unsigned short*)(ws + 8388608);
  unsigned short* w2l = (unsigned short*)(ws + 12582912);
  int* atom_order = (int*)(ws + 16777216);
  int* grp_sp     = (int*)(ws + 16777216 + 16384);
  int* grp_base   = (int*)(ws + 16777216 + 16384 + 4352);
  int* grp_cnt    = (int*)(ws + 16777216 + 16384 + 8704);
  int* n_groups   = (int*)(ws + 16777216 + 16384 + 13056);

  hipLaunchKernelGGL(wsplit_kernel, dim3(1024), dim3(256), 0, stream,
                     W1, W2, w1h, w1l, w2h, w2l);
  hipLaunchKernelGGL(sort_kernel, dim3(1), dim3(256), 0, stream,
                     sp, atom_order, grp_sp, grp_base, grp_cnt, n_groups);
  hipLaunchKernelGGL(mlp_kernel, dim3(MAX_GROUPS), dim3(256), 0, stream,
                     feat, b1, b2, w1h, w1l, w2h, w2l,
                     atom_order, grp_sp, grp_base, grp_cnt, n_groups, out);
}

// Round 4
// 202.991 us; speedup vs baseline: 1.1363x; 1.1363x over previous
//
#include <hip/hip_runtime.h>

typedef __attribute__((ext_vector_type(8))) short short8;
typedef __attribute__((ext_vector_type(4))) float f32x4;

#define N_ATOMS 4096
#define N_NEIGH 32
#define IN_F 128
#define HID 256
#define OUT_F 128
#define N_SPECIES 64
#define GRP 4
#define MAX_GROUPS 1088  // sum ceil(c_s/4) <= 4096/4 + 63

// Truncation-based hi/lo split: hi = top 16 bits (exact chop), lo = (v - hi)
// truncated to bf16. v - hi is exact in fp32 (<=16 mantissa bits), so total
// representation error <= 2^-16 |v|  (vs 2^-17 for RNE, at ~2.5x fewer VALU ops).
struct HL { short h, l; };
__device__ __forceinline__ HL split2(float v) {
  unsigned u = __float_as_uint(v);
  float lo = v - __uint_as_float(u & 0xFFFF0000u);
  HL o;
  o.h = (short)(u >> 16);
  o.l = (short)(__float_as_uint(lo) >> 16);
  return o;
}

// ---------- kernel 1: (block 0) counting sort | (blocks 1..) W split ----------
__global__ __launch_bounds__(256) void prep_kernel(
    const float* __restrict__ W1, const float* __restrict__ W2,
    const int* __restrict__ sp_idx,
    unsigned short* __restrict__ w1h, unsigned short* __restrict__ w1l,
    unsigned short* __restrict__ w2h, unsigned short* __restrict__ w2l,
    int* __restrict__ atom_order, int* __restrict__ grp_sp,
    int* __restrict__ grp_base, int* __restrict__ grp_cnt,
    int* __restrict__ n_groups) {
  const int t = threadIdx.x;
  if (blockIdx.x == 0) {
    __shared__ int cnt[N_SPECIES], off[N_SPECIES], cur[N_SPECIES], gb[N_SPECIES];
    if (t < N_SPECIES) cnt[t] = 0;
    __syncthreads();
    for (int a = t; a < N_ATOMS; a += 256) atomicAdd(&cnt[sp_idx[a]], 1);
    __syncthreads();
    if (t == 0) {
      int o = 0, g = 0;
      for (int s = 0; s < N_SPECIES; ++s) {
        off[s] = o; cur[s] = o; gb[s] = g;
        o += cnt[s];
        g += (cnt[s] + GRP - 1) / GRP;
      }
      *n_groups = g;
    }
    __syncthreads();
    for (int a = t; a < N_ATOMS; a += 256) {
      int s = sp_idx[a];
      atom_order[atomicAdd(&cur[s], 1)] = a;
    }
    if (t < N_SPECIES) {
      const int c = cnt[t], base = off[t], g0 = gb[t];
      const int ng = (c + GRP - 1) / GRP;
      for (int j = 0; j < ng; ++j) {
        grp_sp[g0 + j]   = t;
        grp_base[g0 + j] = base + j * GRP;
        grp_cnt[g0 + j]  = min(GRP, c - j * GRP);
      }
    }
    return;
  }
  const int NV = (N_SPECIES * HID * IN_F) / 4;  // float4 count per matrix
  const int nsplit = (gridDim.x - 1) * 256;
  for (int v = (blockIdx.x - 1) * 256 + t; v < 2 * NV; v += nsplit) {
    const float4* src; unsigned short* dh; unsigned short* dl; int j;
    if (v < NV) { src = (const float4*)W1; dh = w1h; dl = w1l; j = v; }
    else        { src = (const float4*)W2; dh = w2h; dl = w2l; j = v - NV; }
    float4 f = src[j];
    float vv[4] = {f.x, f.y, f.z, f.w};
    ushort4 h, l;
    HL s0 = split2(vv[0]); h.x = (unsigned short)s0.h; l.x = (unsigned short)s0.l;
    HL s1 = split2(vv[1]); h.y = (unsigned short)s1.h; l.y = (unsigned short)s1.l;
    HL s2 = split2(vv[2]); h.z = (unsigned short)s2.h; l.z = (unsigned short)s2.l;
    HL s3 = split2(vv[3]); h.w = (unsigned short)s3.h; l.w = (unsigned short)s3.l;
    ((ushort4*)dh)[j] = h;
    ((ushort4*)dl)[j] = l;
  }
}

// ---------- kernel 2: fused 2-layer MLP, 1 block = 4 waves = 4 atoms ----------
// LDS: double-buffered W chunks in MFMA-fragment order (conflict-free b128 reads)
//      2buf x (w1 hi+lo 16KB + w2 hi+lo 16KB) = 64 KB, + per-wave x tile 16 KB = 80 KB
__global__ __launch_bounds__(256, 2) void mlp_kernel(
    const float* __restrict__ feat,
    const float* __restrict__ b1g, const float* __restrict__ b2g,
    const unsigned short* __restrict__ w1h, const unsigned short* __restrict__ w1l,
    const unsigned short* __restrict__ w2h, const unsigned short* __restrict__ w2l,
    const int* __restrict__ atom_order, const int* __restrict__ grp_sp,
    const int* __restrict__ grp_base, const int* __restrict__ grp_cnt,
    const int* __restrict__ n_groups,
    float* __restrict__ out) {
  const int g = blockIdx.x;
  if (g >= *n_groups) return;
  const int s = grp_sp[g];
  const int abase = grp_base[g];
  const int cnt = grp_cnt[g];
  const int tid = threadIdx.x;
  const int wave = tid >> 6, lane = tid & 63;
  const int q = lane >> 4, r = lane & 15;

  __shared__ short8 lw1[2][2][512];        // [buf][hi/lo][slot = (ks*2+ht)*64 + r*4+q]
  __shared__ short8 lw2[2][2][512];        // [buf][hi/lo][slot = ot*64 + r*4+q]
  __shared__ float lx[4][N_NEIGH * 32];    // per-wave [n(32) x h_local(32)] fp32, swizzled

  const bool active = (wave < cnt);
  int atom = 0;

  // ---- hc-invariant per-lane staging source offsets (fragment-order gather).
  // Wave w stages plane w: 0=w1h 1=w1l 2=w2h 3=w2l; 8 KB (512 frags) each, 8 iters.
  int srcoff[8];
  const char* gplane;
  int hcstride;
  if (wave < 2) {
    gplane = (const char*)(wave == 0 ? w1h : w1l) + (long)s * (HID * IN_F) * 2;
    hcstride = 32 * IN_F * 2;  // 8192 B: 32 hidden rows per chunk
#pragma unroll
    for (int it = 0; it < 8; ++it) {
      const int d = it * 64 + lane;
      const int ks = d >> 7, ht = (d >> 6) & 1, rr = (d >> 2) & 15, qq = d & 3;
      srcoff[it] = (16 * ht + rr) * (IN_F * 2) + (32 * ks + 8 * qq) * 2;
    }
  } else {
    gplane = (const char*)(wave == 2 ? w2h : w2l) + (long)s * (OUT_F * HID) * 2;
    hcstride = 32 * 2;  // 64 B: column-slice step within each o row
#pragma unroll
    for (int it = 0; it < 8; ++it) {
      const int d = it * 64 + lane;
      const int ot = d >> 6, rr = (d >> 2) & 15, qq = d & 3;
      srcoff[it] = (16 * ot + rr) * (HID * 2) + qq * 16;
    }
  }
  short8* dst0 = (wave < 2) ? &lw1[0][wave][0] : &lw2[0][wave - 2][0];

  auto STAGE = [&](int buf, int hc) {
    const char* base = gplane + hc * hcstride;
    short8* dst = dst0 + buf * 1024;
#pragma unroll
    for (int it = 0; it < 8; ++it) {
      __builtin_amdgcn_global_load_lds(
          (const __attribute__((address_space(1))) unsigned int*)(base + srcoff[it]),
          (__attribute__((address_space(3))) unsigned int*)(dst + it * 64 + lane),
          16, 0, 0);
    }
  };

  // ---- kick off chunk 0 staging before doing per-atom prologue work
  STAGE(0, 0);

  // Feature A-fragments (registers, whole kernel): rows 16*nt + r, k = 32*ks + 8*q + j
  short8 fh[2][4], fl[2][4];
  if (active) {
    atom = atom_order[abase + wave];
    const float* fb = feat + (long)atom * (N_NEIGH * IN_F);
#pragma unroll
    for (int nt = 0; nt < 2; ++nt)
#pragma unroll
      for (int ks = 0; ks < 4; ++ks) {
        const float* p = fb + (16 * nt + r) * IN_F + 32 * ks + 8 * q;
        float4 v0 = *(const float4*)p;
        float4 v1 = *(const float4*)(p + 4);
        float vv[8] = {v0.x, v0.y, v0.z, v0.w, v1.x, v1.y, v1.z, v1.w};
        short8 h8, l8;
#pragma unroll
        for (int j = 0; j < 8; ++j) {
          HL hl = split2(vv[j]);
          h8[j] = hl.h;
          l8[j] = hl.l;
        }
        fh[nt][ks] = h8;
        fl[nt][ks] = l8;
      }
  }

  float b2v[8];
#pragma unroll
  for (int ot = 0; ot < 8; ++ot) b2v[ot] = b2g[s * OUT_F + 16 * ot + r];

  f32x4 oacc[2][8] = {};
  char* lxw = (char*)lx[wave];
  const int slotbase = r * 4 + q;

  asm volatile("s_waitcnt vmcnt(0)" ::: "memory");
  __syncthreads();

  for (int hc = 0; hc < 8; ++hc) {
    const int buf = hc & 1;
    if (hc < 7) STAGE(buf ^ 1, hc + 1);  // prefetch next chunk under this chunk's compute

    if (active) {
      // ---- layer 1: x[32 x 32chunk] = feat(32x128) @ W1chunk^T, 3-term hi/lo split
      f32x4 xacc[2][2] = {};
#pragma unroll
      for (int ks = 0; ks < 4; ++ks)
#pragma unroll
        for (int ht = 0; ht < 2; ++ht) {
          short8 bh = lw1[buf][0][(ks * 2 + ht) * 64 + slotbase];
          short8 bl = lw1[buf][1][(ks * 2 + ht) * 64 + slotbase];
#pragma unroll
          for (int nt = 0; nt < 2; ++nt) {
            xacc[nt][ht] = __builtin_amdgcn_mfma_f32_16x16x32_bf16(fh[nt][ks], bh, xacc[nt][ht], 0, 0, 0);
            xacc[nt][ht] = __builtin_amdgcn_mfma_f32_16x16x32_bf16(fh[nt][ks], bl, xacc[nt][ht], 0, 0, 0);
            xacc[nt][ht] = __builtin_amdgcn_mfma_f32_16x16x32_bf16(fl[nt][ks], bh, xacc[nt][ht], 0, 0, 0);
          }
        }
      // ---- bias + SiLU, write per-wave x tile (fp32, swizzled; 2-way max on banks)
#pragma unroll
      for (int ht = 0; ht < 2; ++ht) {
        const float b1v = b1g[s * HID + hc * 32 + 16 * ht + r];
#pragma unroll
        for (int nt = 0; nt < 2; ++nt)
#pragma unroll
          for (int i = 0; i < 4; ++i) {
            const int n = 16 * nt + 4 * q + i;
            float v = xacc[nt][ht][i] + b1v;
            v = v * __builtin_amdgcn_rcpf(1.0f + __expf(-v));
            int byte = (n << 7) + ((r + 16 * ht) << 2);
            byte ^= (n & 7) << 4;
            *(float*)(lxw + byte) = v;
          }
      }
      // ---- read back as layer-2 A-frags (row n = 16*nt + r, k = 8*q + j), split hi/lo
      short8 ah[2], al[2];
#pragma unroll
      for (int nt = 0; nt < 2; ++nt) {
        const int n = 16 * nt + r;
        const int base_b = (n << 7) + (q << 5);
        const int swz = (n & 7) << 4;
        float4 v0 = *(const float4*)(lxw + (base_b ^ swz));
        float4 v1 = *(const float4*)(lxw + ((base_b + 16) ^ swz));
        float vv[8] = {v0.x, v0.y, v0.z, v0.w, v1.x, v1.y, v1.z, v1.w};
        short8 h8, l8;
#pragma unroll
        for (int j = 0; j < 8; ++j) {
          HL hl = split2(vv[j]);
          h8[j] = hl.h;
          l8[j] = hl.l;
        }
        ah[nt] = h8;
        al[nt] = l8;
      }
      // ---- layer 2 partial: out += silu_x_chunk @ W2chunk^T
#pragma unroll
      for (int ot = 0; ot < 8; ++ot) {
        short8 bh = lw2[buf][0][ot * 64 + slotbase];
        short8 bl = lw2[buf][1][ot * 64 + slotbase];
#pragma unroll
        for (int nt = 0; nt < 2; ++nt) {
          oacc[nt][ot] = __builtin_amdgcn_mfma_f32_16x16x32_bf16(ah[nt], bh, oacc[nt][ot], 0, 0, 0);
          oacc[nt][ot] = __builtin_amdgcn_mfma_f32_16x16x32_bf16(ah[nt], bl, oacc[nt][ot], 0, 0, 0);
          oacc[nt][ot] = __builtin_amdgcn_mfma_f32_16x16x32_bf16(al[nt], bh, oacc[nt][ot], 0, 0, 0);
        }
      }
    }
    // staged loads for hc+1 were issued ~2.5k cycles ago; this drain is cheap
    asm volatile("s_waitcnt vmcnt(0)" ::: "memory");
    __syncthreads();
  }

  if (active) {
    float* ob = out + (long)atom * (N_NEIGH * OUT_F);
#pragma unroll
    for (int nt = 0; nt < 2; ++nt)
#pragma unroll
      for (int ot = 0; ot < 8; ++ot)
#pragma unroll
        for (int i = 0; i < 4; ++i) {
          ob[(16 * nt + 4 * q + i) * OUT_F + 16 * ot + r] = oacc[nt][ot][i] + b2v[ot];
        }
  }
}

extern "C" void kernel_launch(void* const* d_in, const int* in_sizes, int n_in,
                              void* d_out, int out_size, void* d_ws, size_t ws_size,
                              hipStream_t stream) {
  const float* feat = (const float*)d_in[0];
  const int* sp     = (const int*)d_in[1];
  const float* W1   = (const float*)d_in[2];
  const float* b1   = (const float*)d_in[3];
  const float* W2   = (const float*)d_in[4];
  const float* b2   = (const float*)d_in[5];
  float* out = (float*)d_out;

  char* ws = (char*)d_ws;
  unsigned short* w1h = (unsigned short*)(ws + 0);
  unsigned short* w1l = (unsigned short*)(ws + 4194304);
  unsigned short* w2h = (unsigned short*)(ws + 8388608);
  unsigned short* w2l = (unsigned short*)(ws + 12582912);
  int* atom_order = (int*)(ws + 16777216);
  int* grp_sp     = (int*)(ws + 16777216 + 16384);
  int* grp_base   = (int*)(ws + 16777216 + 16384 + 4352);
  int* grp_cnt    = (int*)(ws + 16777216 + 16384 + 8704);
  int* n_groups   = (int*)(ws + 16777216 + 16384 + 13056);

  hipLaunchKernelGGL(prep_kernel, dim3(1025), dim3(256), 0, stream,
                     W1, W2, sp, w1h, w1l, w2h, w2l,
                     atom_order, grp_sp, grp_base, grp_cnt, n_groups);
  hipLaunchKernelGGL(mlp_kernel, dim3(MAX_GROUPS), dim3(256), 0, stream,
                     feat, b1, b2, w1h, w1l, w2h, w2l,
                     atom_order, grp_sp, grp_base, grp_cnt, n_groups, out);
}